// Round 10
// baseline (324.315 us; speedup 1.0000x reference)
//
#include <hip/hip_runtime.h>

#define LL 4
#define BB 32
#define SS 512
#define FF 768
#define NW 257        // W_MAX + 1
#define F4 192        // FF / 4
#define NSLOT 32      // 16-boundary slots per row (slot k = boundary at s=16k)

typedef float f4v __attribute__((ext_vector_type(4)));   // clang vector: nontemporal-ok

// ---- main: layer-mix + run-compressed segment-MEAN + sentence partials ----
// grid: BB * 8 * 3 blocks of 256 threads
// block -> (b, sg in 0..7 [64 s each], fc in 0..2 [64 float4 each])
// thread t: lane = t&63 -> f4 = fc*64+lane ; swave = t>>6 -> s in [s0, s0+16)
//
// Word spans are contiguous (sorted ids). A run fully inside a thread's 16-s
// window is the word's COMPLETE span -> store mean directly to out (no init
// needed). Boundary-crossing words have NO exclusive portion; their partial
// sums go to compact L2-resident bsum[b][slot][f] via atomics:
//   left-shared first run  -> slot i   (boundary at s0)
//   right-shared final run -> slot i+1 (boundary at s0+16)
//   full-window single run -> slot i if left-shared else i+1
// k_fix rebuilds boundary words from bsum (write-only on out).
__global__ __launch_bounds__(256, 3)
void k_main(const float* __restrict__ hs, const float* __restrict__ lw,
            const float* __restrict__ gm, const int* __restrict__ wid,
            float* __restrict__ out, float* __restrict__ bsum,
            float* __restrict__ partials) {
    int bid = blockIdx.x;
    int fc = bid % 3;
    int sg = (bid / 3) & 7;
    int b  = bid / 24;
    int t = threadIdx.x;
    int lane = t & 63;
    int swave = t >> 6;
    int f4 = fc * 64 + lane;
    int s0 = sg * 64 + swave * 16;
    int win = s0 >> 4;                            // window index 0..31

    // softmax(layer_weights) * gamma  (tiny, all-lane broadcast loads)
    float w0 = lw[0], w1 = lw[1], w2 = lw[2], w3 = lw[3];
    float mx = fmaxf(fmaxf(w0, w1), fmaxf(w2, w3));
    float e0 = __expf(w0 - mx), e1 = __expf(w1 - mx);
    float e2 = __expf(w2 - mx), e3 = __expf(w3 - mx);
    float g = gm[0] / (e0 + e1 + e2 + e3);
    float c0 = e0 * g, c1 = e1 * g, c2 = e2 * g, c3 = e3 * g;

    const f4v* h4 = (const f4v*)hs;
    const int ls = BB * SS * F4;                  // layer stride in 16B units
    int base = (b * SS + s0) * F4 + f4;
    const int* wrow = wid + b * SS + s0;

    int prev = wrow[0];
    // shared-across-boundary flags (wave-uniform)
    bool sharedL = (s0 > 0) && (wrow[-1] == prev);
    bool sharedR = (s0 + 16 < SS) && (wrow[16] == wrow[15]);

    f4v sent = {0.f, 0.f, 0.f, 0.f};
    f4v run  = {0.f, 0.f, 0.f, 0.f};
    int len = 0;
    bool first = true;

    #pragma unroll
    for (int k = 0; k < 16; k++) {
        int w = wrow[k];                          // wave-uniform (all lanes same s)
        int idx = base + k * F4;
        f4v a  = __builtin_nontemporal_load(&h4[idx]);
        f4v bv = __builtin_nontemporal_load(&h4[idx + ls]);
        f4v cv = __builtin_nontemporal_load(&h4[idx + 2 * ls]);
        f4v dv = __builtin_nontemporal_load(&h4[idx + 3 * ls]);
        f4v v = c0 * a + c1 * bv + c2 * cv + c3 * dv;
        sent += v;
        if (w != prev) {                          // wave-uniform branch
            if (first && sharedL) {               // left-shared first run -> slot win
                float* p = bsum + ((size_t)(b * NSLOT + win) * FF) + f4 * 4;
                atomicAdd(p + 0, run.x); atomicAdd(p + 1, run.y);
                atomicAdd(p + 2, run.z); atomicAdd(p + 3, run.w);
            } else {                              // complete span: store mean
                float* p = out + (prev + b * NW) * FF + f4 * 4;
                *(f4v*)p = run * (1.0f / (float)len);
            }
            first = false;
            run = v; len = 1; prev = w;
        } else {
            run += v; len++;
        }
    }
    {   // final run
        if (first && sharedL) {                   // spans left boundary -> slot win
            float* p = bsum + ((size_t)(b * NSLOT + win) * FF) + f4 * 4;
            atomicAdd(p + 0, run.x); atomicAdd(p + 1, run.y);
            atomicAdd(p + 2, run.z); atomicAdd(p + 3, run.w);
        } else if (sharedR) {                     // spans right boundary -> slot win+1
            float* p = bsum + ((size_t)(b * NSLOT + win + 1) * FF) + f4 * 4;
            atomicAdd(p + 0, run.x); atomicAdd(p + 1, run.y);
            atomicAdd(p + 2, run.z); atomicAdd(p + 3, run.w);
        } else {
            float* p = out + (prev + b * NW) * FF + f4 * 4;
            *(f4v*)p = run * (1.0f / (float)len);
        }
    }

    // sentence partial: reduce the 4 s-waves, one non-atomic store per (b,sg,f4)
    __shared__ f4v sm[256];
    sm[t] = sent;
    __syncthreads();
    if (t < 64) {
        f4v tot = sm[t] + sm[t + 64] + sm[t + 128] + sm[t + 192];
        ((f4v*)partials)[(b * 8 + sg) * F4 + f4] = tot;   // f4 == fc*64 + t
    }
}

// ---- fixup: boundary words from bsum, zeros for empty words, sentence mean ----
// grid: BB blocks of 512 threads (8 waves; wave-parallel word loop)
__global__ void k_fix(const int* __restrict__ wid,
                      const float* __restrict__ bsum,
                      const float* __restrict__ partials,
                      float* __restrict__ out) {
    __shared__ int wrow[SS];
    __shared__ int lc[NW];
    __shared__ int bw[NSLOT];                     // slot owner word (-1 unused)
    int b = blockIdx.x;
    int t = threadIdx.x;
    for (int i = t; i < NW; i += 512) lc[i] = 0;
    __syncthreads();
    int w = wid[b * SS + t];
    wrow[t] = w;
    atomicAdd(&lc[w], 1);
    __syncthreads();
    if (t < NSLOT)
        bw[t] = (t >= 1 && wrow[16 * t - 1] == wrow[16 * t]) ? wrow[16 * t] : -1;
    __syncthreads();

    int wave = t >> 6;                            // 0..7
    int lane = t & 63;
    const f4v* bs4 = (const f4v*)(bsum + (size_t)b * NSLOT * FF);
    for (int w2 = 1 + wave; w2 < NW; w2 += 8) {   // wave-parallel over words
        int c = lc[w2];
        f4v* po = (f4v*)(out + ((size_t)b * NW + w2) * FF);
        if (c == 0) {                             // empty word -> zeros
            f4v z = {0.f, 0.f, 0.f, 0.f};
            #pragma unroll
            for (int i = 0; i < 3; i++) po[lane + 64 * i] = z;
        } else {
            // boundary word? sum its slots (LDS broadcast scan, wave-uniform)
            bool has = false;
            f4v acc0 = {0.f,0.f,0.f,0.f}, acc1 = acc0, acc2 = acc0;
            for (int k = 1; k < NSLOT; k++) {
                if (bw[k] == w2) {
                    has = true;
                    const f4v* pb = bs4 + (size_t)k * F4;
                    acc0 += pb[lane];
                    acc1 += pb[lane + 64];
                    acc2 += pb[lane + 128];
                }
            }
            if (has) {
                float inv = 1.0f / (float)c;
                po[lane]       = acc0 * inv;
                po[lane + 64]  = acc1 * inv;
                po[lane + 128] = acc2 * inv;
            }
            // else: exclusive word, already written by k_main
        }
    }

    // sentence mean into slot 0
    __syncthreads();
    if (t < F4) {
        const f4v* pp = (const f4v*)(partials + (size_t)b * 8 * FF);
        f4v s = {0.f, 0.f, 0.f, 0.f};
        #pragma unroll
        for (int gg = 0; gg < 8; gg++) s += pp[(size_t)gg * F4 + t];
        ((f4v*)(out + (size_t)b * NW * FF))[t] = s * (1.0f / (float)SS);
    }
}

extern "C" void kernel_launch(void* const* d_in, const int* in_sizes, int n_in,
                              void* d_out, int out_size, void* d_ws, size_t ws_size,
                              hipStream_t stream) {
    const float* hs  = (const float*)d_in[0];   // (L,B,S,F) f32
    const float* lw  = (const float*)d_in[1];   // (L,)
    const float* gm  = (const float*)d_in[2];   // (1,)
    const int*   wid = (const int*)d_in[3];     // (B,S) int32, sorted per row
    float* out = (float*)d_out;                 // (B, 257, F) f32

    float* bsum     = (float*)d_ws;                                  // BB*NSLOT*FF f32 = 3.1 MB
    float* partials = bsum + (size_t)BB * NSLOT * FF;                // BB*8*FF f32 = 786 KB

    (void)hipMemsetAsync(bsum, 0, (size_t)BB * NSLOT * FF * sizeof(float), stream);
    k_main<<<BB * 24, 256, 0, stream>>>(hs, lw, gm, wid, out, bsum, partials);
    k_fix<<<BB, 512, 0, stream>>>(wid, bsum, partials, out);
}

// Round 11
// 321.637 us; speedup vs baseline: 1.0083x; 1.0083x over previous
//
#include <hip/hip_runtime.h>

#define LL 4
#define BB 32
#define SS 512
#define FF 768
#define NW 257        // W_MAX + 1
#define F4 192        // FF / 4
#define NSLOT 32      // 16-boundary slots per row (slot k = boundary at s=16k)

typedef float f4v __attribute__((ext_vector_type(4)));   // clang vector: nontemporal-ok

// ---- main: layer-mix + run-compressed segment-MEAN + sentence partials ----
// grid: BB * 8 * 3 blocks of 256 threads
// block -> (b, sg in 0..7 [64 s each], fc in 0..2 [64 float4 each])
// thread t: lane = t&63 -> f4 = fc*64+lane ; swave = t>>6 -> s in [s0, s0+16)
//
// PHASE 1 (branch-free, store-free): stream 16 s-steps x 4 layers into v[16]
// registers — maximal memory-level parallelism, no CFG breaks.
// PHASE 2 (register-only): run-compress v[] over word boundaries.
//   complete span inside window -> direct mean store to out
//   boundary-shared portions    -> atomicAdd into compact bsum[b][slot][f]
__global__ __launch_bounds__(256, 3)
void k_main(const float* __restrict__ hs, const float* __restrict__ lw,
            const float* __restrict__ gm, const int* __restrict__ wid,
            float* __restrict__ out, float* __restrict__ bsum,
            float* __restrict__ partials) {
    int bid = blockIdx.x;
    int fc = bid % 3;
    int sg = (bid / 3) & 7;
    int b  = bid / 24;
    int t = threadIdx.x;
    int lane = t & 63;
    int swave = t >> 6;
    int f4 = fc * 64 + lane;
    int s0 = sg * 64 + swave * 16;
    int win = s0 >> 4;                            // window index 0..31

    // softmax(layer_weights) * gamma  (tiny, all-lane broadcast loads)
    float w0 = lw[0], w1 = lw[1], w2 = lw[2], w3 = lw[3];
    float mx = fmaxf(fmaxf(w0, w1), fmaxf(w2, w3));
    float e0 = __expf(w0 - mx), e1 = __expf(w1 - mx);
    float e2 = __expf(w2 - mx), e3 = __expf(w3 - mx);
    float g = gm[0] / (e0 + e1 + e2 + e3);
    float c0 = e0 * g, c1 = e1 * g, c2 = e2 * g, c3 = e3 * g;

    const f4v* h4 = (const f4v*)hs;
    const int ls = BB * SS * F4;                  // layer stride in 16B units
    int base = (b * SS + s0) * F4 + f4;
    const int* wrow = wid + b * SS + s0;

    // ---- PHASE 1: pure streaming ----
    f4v v[16];
    f4v sent = {0.f, 0.f, 0.f, 0.f};
    #pragma unroll
    for (int k = 0; k < 16; k++) {
        int idx = base + k * F4;
        f4v a  = __builtin_nontemporal_load(&h4[idx]);
        f4v bv = __builtin_nontemporal_load(&h4[idx + ls]);
        f4v cv = __builtin_nontemporal_load(&h4[idx + 2 * ls]);
        f4v dv = __builtin_nontemporal_load(&h4[idx + 3 * ls]);
        v[k] = c0 * a + c1 * bv + c2 * cv + c3 * dv;
        sent += v[k];
    }

    // ---- PHASE 2: register-only run-compress ----
    int prev = wrow[0];
    bool sharedL = (s0 > 0) && (wrow[-1] == prev);
    bool sharedR = (s0 + 16 < SS) && (wrow[16] == wrow[15]);

    f4v run = {0.f, 0.f, 0.f, 0.f};
    int len = 0;
    bool first = true;
    #pragma unroll
    for (int k = 0; k < 16; k++) {
        int w = wrow[k];                          // wave-uniform, L1/L2-hot
        if (w != prev) {
            if (first && sharedL) {               // left-shared first run -> slot win
                float* p = bsum + ((size_t)(b * NSLOT + win) * FF) + f4 * 4;
                atomicAdd(p + 0, run.x); atomicAdd(p + 1, run.y);
                atomicAdd(p + 2, run.z); atomicAdd(p + 3, run.w);
            } else {                              // complete span: store mean
                float* p = out + (prev + b * NW) * FF + f4 * 4;
                *(f4v*)p = run * (1.0f / (float)len);
            }
            first = false;
            run = v[k]; len = 1; prev = w;
        } else {
            run += v[k]; len++;
        }
    }
    {   // final run
        if (first && sharedL) {                   // spans left boundary -> slot win
            float* p = bsum + ((size_t)(b * NSLOT + win) * FF) + f4 * 4;
            atomicAdd(p + 0, run.x); atomicAdd(p + 1, run.y);
            atomicAdd(p + 2, run.z); atomicAdd(p + 3, run.w);
        } else if (sharedR) {                     // spans right boundary -> slot win+1
            float* p = bsum + ((size_t)(b * NSLOT + win + 1) * FF) + f4 * 4;
            atomicAdd(p + 0, run.x); atomicAdd(p + 1, run.y);
            atomicAdd(p + 2, run.z); atomicAdd(p + 3, run.w);
        } else {
            float* p = out + (prev + b * NW) * FF + f4 * 4;
            *(f4v*)p = run * (1.0f / (float)len);
        }
    }

    // sentence partial: reduce the 4 s-waves, one non-atomic store per (b,sg,f4)
    __shared__ f4v sm[256];
    sm[t] = sent;
    __syncthreads();
    if (t < 64) {
        f4v tot = sm[t] + sm[t + 64] + sm[t + 128] + sm[t + 192];
        ((f4v*)partials)[(b * 8 + sg) * F4 + f4] = tot;   // f4 == fc*64 + t
    }
}

// ---- fixup: boundary words from bsum, zeros for empty words, sentence mean ----
// grid: BB*8 blocks of 256 threads; block -> (b, 32-word chunk)
__global__ void k_fix(const int* __restrict__ wid,
                      const float* __restrict__ bsum,
                      const float* __restrict__ partials,
                      float* __restrict__ out) {
    __shared__ int wrow[SS];
    __shared__ int lc[NW];
    __shared__ int bw[NSLOT];                     // slot owner word (-1 unused)
    int b = blockIdx.x >> 3;
    int chunk = blockIdx.x & 7;
    int t = threadIdx.x;
    for (int i = t; i < NW; i += 256) lc[i] = 0;
    __syncthreads();
    #pragma unroll
    for (int j = 0; j < 2; j++) {
        int s = t + j * 256;
        int w = wid[b * SS + s];
        wrow[s] = w;
        atomicAdd(&lc[w], 1);
    }
    __syncthreads();
    if (t < NSLOT)
        bw[t] = (t >= 1 && wrow[16 * t - 1] == wrow[16 * t]) ? wrow[16 * t] : -1;
    __syncthreads();

    int wave = t >> 6;                            // 0..3
    int lane = t & 63;
    const f4v* bs4 = (const f4v*)(bsum + (size_t)b * NSLOT * FF);
    for (int i = wave; i < 32; i += 4) {          // 32 words per chunk
        int w2 = 1 + chunk * 32 + i;
        int c = lc[w2];
        f4v* po = (f4v*)(out + ((size_t)b * NW + w2) * FF);
        if (c == 0) {                             // empty word -> zeros
            f4v z = {0.f, 0.f, 0.f, 0.f};
            #pragma unroll
            for (int q = 0; q < 3; q++) po[lane + 64 * q] = z;
        } else {
            // boundary word? sum its slots (LDS broadcast scan, wave-uniform)
            bool has = false;
            f4v acc0 = {0.f,0.f,0.f,0.f}, acc1 = acc0, acc2 = acc0;
            for (int k = 1; k < NSLOT; k++) {
                if (bw[k] == w2) {
                    has = true;
                    const f4v* pb = bs4 + (size_t)k * F4;
                    acc0 += pb[lane];
                    acc1 += pb[lane + 64];
                    acc2 += pb[lane + 128];
                }
            }
            if (has) {
                float inv = 1.0f / (float)c;
                po[lane]       = acc0 * inv;
                po[lane + 64]  = acc1 * inv;
                po[lane + 128] = acc2 * inv;
            }
            // else: exclusive word, already written by k_main
        }
    }

    // sentence mean into slot 0 (one chunk per b does it)
    if (chunk == 0 && t < F4) {
        const f4v* pp = (const f4v*)(partials + (size_t)b * 8 * FF);
        f4v s = {0.f, 0.f, 0.f, 0.f};
        #pragma unroll
        for (int gg = 0; gg < 8; gg++) s += pp[(size_t)gg * F4 + t];
        ((f4v*)(out + (size_t)b * NW * FF))[t] = s * (1.0f / (float)SS);
    }
}

extern "C" void kernel_launch(void* const* d_in, const int* in_sizes, int n_in,
                              void* d_out, int out_size, void* d_ws, size_t ws_size,
                              hipStream_t stream) {
    const float* hs  = (const float*)d_in[0];   // (L,B,S,F) f32
    const float* lw  = (const float*)d_in[1];   // (L,)
    const float* gm  = (const float*)d_in[2];   // (1,)
    const int*   wid = (const int*)d_in[3];     // (B,S) int32, sorted per row
    float* out = (float*)d_out;                 // (B, 257, F) f32

    float* bsum     = (float*)d_ws;                                  // BB*NSLOT*FF f32 = 3.1 MB
    float* partials = bsum + (size_t)BB * NSLOT * FF;                // BB*8*FF f32 = 786 KB

    (void)hipMemsetAsync(bsum, 0, (size_t)BB * NSLOT * FF * sizeof(float), stream);
    k_main<<<BB * 24, 256, 0, stream>>>(hs, lw, gm, wid, out, bsum, partials);
    k_fix<<<BB * 8, 256, 0, stream>>>(wid, bsum, partials, out);
}

// Round 12
// 290.791 us; speedup vs baseline: 1.1153x; 1.1061x over previous
//
#include <hip/hip_runtime.h>

#define BB 32
#define SS 512
#define FF 768
#define NW 257        // W_MAX + 1
#define F4 192        // FF / 4
#define WIN 8         // s-positions per thread window
#define NWIN 64       // SS / WIN

typedef float f4v __attribute__((ext_vector_type(4)));

// ---- main: layer-mix + run-compressed segment-MEAN, L/R window sums ----
// grid: BB*16*3 blocks of 256 (bid = b*48 + sg*3 + fc)
// block: 4 waves(swave: 8 s each) x 64 lanes(f4 = fc*64+lane) -> 32 s x 1KB
//
// Every window writes L[b][win] (prefix-run sum) and R[b][win] (suffix-run
// sum) unconditionally -> unique writer, no atomics, no zero-init.
// Complete-inside-window words: direct mean store to out.
// Boundary-crossing words: k_fix computes R[i] + sum L[i+1..j].
__global__ __launch_bounds__(256, 6)
void k_main(const float* __restrict__ hs, const float* __restrict__ lw,
            const float* __restrict__ gm, const int* __restrict__ wid,
            float* __restrict__ out, float* __restrict__ lr,
            float* __restrict__ partials) {
    int bid = blockIdx.x;
    int fc = bid % 3;
    int sg = (bid / 3) & 15;
    int b  = bid / 48;
    int t = threadIdx.x;
    int lane = t & 63;
    int swave = t >> 6;
    int f4 = fc * 64 + lane;
    int s0 = sg * 32 + swave * 8;
    int win = s0 >> 3;                            // 0..63

    // softmax(layer_weights) * gamma
    float w0 = lw[0], w1 = lw[1], w2 = lw[2], w3 = lw[3];
    float mx = fmaxf(fmaxf(w0, w1), fmaxf(w2, w3));
    float e0 = __expf(w0 - mx), e1 = __expf(w1 - mx);
    float e2 = __expf(w2 - mx), e3 = __expf(w3 - mx);
    float g = gm[0] / (e0 + e1 + e2 + e3);
    float c0 = e0 * g, c1 = e1 * g, c2 = e2 * g, c3 = e3 * g;

    const f4v* h4 = (const f4v*)hs;
    const int ls = BB * SS * F4;                  // layer stride in 16B units
    int base = (b * SS + s0) * F4 + f4;
    const int* wrow = wid + b * SS + s0;

    int prev = wrow[0];
    bool sharedL = (s0 > 0) && (wrow[-1] == prev);
    bool sharedR = (s0 + WIN < SS) && (wrow[WIN] == wrow[WIN - 1]);

    f4v* lrw = (f4v*)lr + (size_t)(b * NWIN + win) * 2 * F4;   // [L|R] this window
    f4v* ob  = (f4v*)out + (size_t)b * NW * F4;

    f4v sent = {0.f, 0.f, 0.f, 0.f};
    f4v run  = {0.f, 0.f, 0.f, 0.f};
    int len = 0;
    bool first = true;

    #pragma unroll
    for (int k = 0; k < WIN; k++) {
        int idx = base + k * F4;
        f4v a  = __builtin_nontemporal_load(&h4[idx]);
        f4v bv = __builtin_nontemporal_load(&h4[idx + ls]);
        f4v cv = __builtin_nontemporal_load(&h4[idx + 2 * ls]);
        f4v dv = __builtin_nontemporal_load(&h4[idx + 3 * ls]);
        f4v v = c0 * a + c1 * bv + c2 * cv + c3 * dv;
        sent += v;
        int w = wrow[k];                          // wave-uniform
        if (k > 0 && w != prev) {
            if (first) {
                lrw[f4] = run;                    // L[win] = prefix-run sum
                if (!sharedL)                     // complete word at left edge
                    ob[(size_t)prev * F4 + f4] = run * (1.0f / (float)len);
            } else {                              // middle run: complete word
                ob[(size_t)prev * F4 + f4] = run * (1.0f / (float)len);
            }
            first = false;
            run = v; len = 1; prev = w;
        } else {
            run += v; len++;
        }
    }
    {   // suffix run
        lrw[F4 + f4] = run;                       // R[win]
        if (first) {                              // single-run window: L = R
            lrw[f4] = run;
            if (!sharedL && !sharedR)
                ob[(size_t)prev * F4 + f4] = run * (1.0f / (float)len);
        } else if (!sharedR) {
            ob[(size_t)prev * F4 + f4] = run * (1.0f / (float)len);
        }
    }

    // sentence partial: reduce 4 s-waves -> partials[b][sg][f]
    __shared__ f4v sm[256];
    sm[t] = sent;
    __syncthreads();
    if (t < 64) {
        f4v tot = sm[t] + sm[t + 64] + sm[t + 128] + sm[t + 192];
        ((f4v*)partials)[((size_t)b * 16 + sg) * F4 + f4] = tot;  // f4==fc*64+t
    }
}

// ---- fixup: crossing words from L/R, zeros for empties, sentence slot 0 ----
// grid: BB*8 blocks of 256; block -> (b, chunk); words w ≡ chunk (mod 8)
__global__ __launch_bounds__(256, 4)
void k_fix(const int* __restrict__ wid,
           const float* __restrict__ lr,
           const float* __restrict__ partials,
           float* __restrict__ out) {
    __shared__ int ww[SS];
    int bid = blockIdx.x;
    int b = bid >> 3;
    int chunk = bid & 7;
    int t = threadIdx.x;
    ww[t]       = wid[b * SS + t];
    ww[t + 256] = wid[b * SS + t + 256];
    __syncthreads();

    int wave = t >> 6, lane = t & 63;
    const f4v* lr4 = (const f4v*)lr + (size_t)b * NWIN * 2 * F4;
    f4v* ob = (f4v*)out + (size_t)b * NW * F4;

    for (int i = wave; i < 32; i += 4) {
        int w2 = 1 + chunk + 8 * i;               // 1..256
        // lower_bound(w2), lower_bound(w2+1) on sorted row (LDS broadcast)
        int lo = 0, hi = SS;
        while (lo < hi) { int m = (lo + hi) >> 1; if (ww[m] < w2) lo = m + 1; else hi = m; }
        int sa = lo;
        lo = 0; hi = SS;
        while (lo < hi) { int m = (lo + hi) >> 1; if (ww[m] < w2 + 1) lo = m + 1; else hi = m; }
        int se = lo - 1;

        f4v* po = ob + (size_t)w2 * F4;
        if (sa > se) {                            // empty word -> zeros
            f4v z = {0.f, 0.f, 0.f, 0.f};
            po[lane] = z; po[lane + 64] = z; po[lane + 128] = z;
        } else {
            int i0 = sa >> 3, j0 = se >> 3;
            if (i0 != j0) {                       // crossing word: R[i0] + sum L
                f4v a0 = lr4[((size_t)i0 * 2 + 1) * F4 + lane];
                f4v a1 = lr4[((size_t)i0 * 2 + 1) * F4 + lane + 64];
                f4v a2 = lr4[((size_t)i0 * 2 + 1) * F4 + lane + 128];
                for (int k = i0 + 1; k <= j0; k++) {
                    a0 += lr4[((size_t)k * 2) * F4 + lane];
                    a1 += lr4[((size_t)k * 2) * F4 + lane + 64];
                    a2 += lr4[((size_t)k * 2) * F4 + lane + 128];
                }
                float inv = 1.0f / (float)(se - sa + 1);
                po[lane] = a0 * inv; po[lane + 64] = a1 * inv; po[lane + 128] = a2 * inv;
            }
            // else: complete word, already written by k_main
        }
    }

    // sentence mean into slot 0 (chunk 0 only)
    if (chunk == 0 && t < F4) {
        const f4v* pp = (const f4v*)partials + (size_t)b * 16 * F4;
        f4v s = {0.f, 0.f, 0.f, 0.f};
        #pragma unroll
        for (int g2 = 0; g2 < 16; g2++) s += pp[(size_t)g2 * F4 + t];
        ob[t] = s * (1.0f / (float)SS);
    }
}

extern "C" void kernel_launch(void* const* d_in, const int* in_sizes, int n_in,
                              void* d_out, int out_size, void* d_ws, size_t ws_size,
                              hipStream_t stream) {
    const float* hs  = (const float*)d_in[0];   // (L,B,S,F) f32
    const float* lw  = (const float*)d_in[1];   // (L,)
    const float* gm  = (const float*)d_in[2];   // (1,)
    const int*   wid = (const int*)d_in[3];     // (B,S) int32, sorted per row
    float* out = (float*)d_out;                 // (B, 257, F) f32

    float* lr       = (float*)d_ws;                          // BB*NWIN*2*FF f32 = 12.6 MB
    float* partials = lr + (size_t)BB * NWIN * 2 * FF;       // BB*16*FF f32 = 1.6 MB

    k_main<<<BB * 48, 256, 0, stream>>>(hs, lw, gm, wid, out, lr, partials);
    k_fix<<<BB * 8, 256, 0, stream>>>(wid, lr, partials, out);
}